// Round 4
// baseline (318.567 us; speedup 1.0000x reference)
//
#include <hip/hip_runtime.h>
#include <hip/hip_bf16.h>
#include <hip/hip_fp8.h>

typedef __bf16 bf16x8 __attribute__((ext_vector_type(8)));
typedef float floatx4 __attribute__((ext_vector_type(4)));

// ---- Cl(3) Cayley table, row i = first operand, col j = second. p = i*8+j ----
constexpr int TK[64] = {
  0,1,2,3,4,5,6,7,
  1,0,4,5,2,3,7,6,
  2,4,0,6,1,7,3,5,
  3,5,6,0,7,1,2,4,
  4,2,1,7,0,6,5,3,
  5,3,7,1,6,0,4,2,
  6,7,3,2,5,4,0,1,
  7,6,5,4,3,2,1,0
};
constexpr float SGN[64] = {
  1, 1, 1, 1, 1, 1, 1, 1,
  1, 1, 1, 1, 1, 1, 1, 1,
  1,-1, 1, 1,-1,-1, 1,-1,
  1,-1,-1, 1, 1,-1,-1, 1,
  1,-1, 1, 1,-1,-1, 1,-1,
  1,-1,-1, 1, 1,-1,-1, 1,
  1, 1,-1, 1,-1, 1,-1,-1,
  1, 1,-1, 1,-1, 1,-1,-1
};

__device__ __forceinline__ void async16(const void* g, void* l) {
  __builtin_amdgcn_global_load_lds(
      (const __attribute__((address_space(1))) void*)g,
      (__attribute__((address_space(3))) void*)l, 16, 0, 0);
}

__device__ __forceinline__ unsigned char to_fp8(float v) {
  __hip_fp8_e4m3 q(v);
  return (unsigned char)q.__x;
}

// ---- transpose+cast fp32 [K][N] -> bf16 [N][K] ----
__global__ __launch_bounds__(256) void transpose_cast(
    const float* __restrict__ src, __bf16* __restrict__ dst, int K, int N)
{
  __shared__ float s[32 * 33];
  const int t = threadIdx.x;
  const int k0 = blockIdx.y * 32, n0 = blockIdx.x * 32;
  const int r = t >> 5, c = t & 31;
  #pragma unroll
  for (int i = 0; i < 4; ++i)
    s[(r + i * 8) * 33 + c] = src[(size_t)(k0 + r + i * 8) * N + n0 + c];
  __syncthreads();
  #pragma unroll
  for (int i = 0; i < 4; ++i)
    dst[(size_t)(n0 + r + i * 8) * K + k0 + c] = (__bf16)s[c * 33 + r + i * 8];
}

// ---- transpose+cast fp32 [K][N] -> fp8 [N][K], value*16 ----
__global__ __launch_bounds__(256) void transpose_cast_fp8(
    const float* __restrict__ src, unsigned char* __restrict__ dst, int K, int N)
{
  __shared__ float s[32 * 33];
  const int t = threadIdx.x;
  const int k0 = blockIdx.y * 32, n0 = blockIdx.x * 32;
  const int r = t >> 5, c = t & 31;
  #pragma unroll
  for (int i = 0; i < 4; ++i)
    s[(r + i * 8) * 33 + c] = src[(size_t)(k0 + r + i * 8) * N + n0 + c];
  __syncthreads();
  #pragma unroll
  for (int i = 0; i < 4; ++i)
    dst[(size_t)(n0 + r + i * 8) * K + k0 + c] = to_fp8(16.f * s[c * 33 + r + i * 8]);
}

// ---- geometric product + gate mix + LayerNorm -> bf16 flat [65536][256] ----
__global__ __launch_bounds__(256) void geo_ln(
    const float* __restrict__ X,   // [8192][8][256]
    const float* __restrict__ IW,  // [64]
    const float* __restrict__ GG,  // [1]
    const float* __restrict__ LW, const float* __restrict__ LB,
    __bf16* __restrict__ F)        // [65536][256]
{
  __shared__ float sw[64];
  __shared__ float smix[8 * 256];
  __shared__ float sstat[16];
  const int t = threadIdx.x;
  const int tok = blockIdx.x;

  if (t < 64) sw[t] = SGN[t] / (1.f + __expf(-IW[t]));

  float xv[8];
  #pragma unroll
  for (int b = 0; b < 8; ++b) xv[b] = X[(size_t)tok * 2048 + b * 256 + t];
  const float g = 1.f / (1.f + __expf(-GG[0]));

  __syncthreads();

  float geo[8] = {0.f, 0.f, 0.f, 0.f, 0.f, 0.f, 0.f, 0.f};
  #pragma unroll
  for (int p = 0; p < 64; ++p)
    geo[TK[p]] += xv[p >> 3] * xv[p & 7] * sw[p];

  float mv[8];
  #pragma unroll
  for (int b = 0; b < 8; ++b) {
    mv[b] = g * geo[b] + (1.f - g) * xv[b];
    smix[b * 256 + t] = mv[b];
  }
  __syncthreads();

  const int wv = t >> 6, lane = t & 63;
  #pragma unroll
  for (int s = 0; s < 2; ++s) {
    int b = wv * 2 + s;
    float v0 = smix[b * 256 + lane];
    float v1 = smix[b * 256 + 64 + lane];
    float v2 = smix[b * 256 + 128 + lane];
    float v3 = smix[b * 256 + 192 + lane];
    float sum = v0 + v1 + v2 + v3;
    float sq  = v0*v0 + v1*v1 + v2*v2 + v3*v3;
    #pragma unroll
    for (int off = 32; off > 0; off >>= 1) {
      sum += __shfl_xor(sum, off, 64);
      sq  += __shfl_xor(sq,  off, 64);
    }
    if (lane == 0) {
      float mu  = sum * (1.f / 256.f);
      float var = sq * (1.f / 256.f) - mu * mu;
      sstat[b]     = mu;
      sstat[8 + b] = rsqrtf(var + 1e-5f);
    }
  }
  __syncthreads();

  const float lw = LW[t], lb = LB[t];
  #pragma unroll
  for (int b = 0; b < 8; ++b) {
    float v = (mv[b] - sstat[b]) * sstat[8 + b] * lw + lb;
    F[(size_t)(tok * 8 + b) * 256 + t] = (__bf16)v;
  }
}

// ---- Kernel C: gate+up GEMM + SwiGLU -> h fp8 [65536][1024] (scaled x16) ----
// tile 128m x 128f, BK=64, XOR-swizzled LDS. grid (8 f, 512 m) x-fastest.
__global__ __launch_bounds__(256, 2) void gemm_gateup(
    const __bf16* __restrict__ A,   // flat [65536][256]
    const __bf16* __restrict__ Bg,  // [1024][256]
    const __bf16* __restrict__ Bu,  // [1024][256]
    unsigned char* __restrict__ H)  // fp8 [65536][1024]
{
  __shared__ __bf16 sA[128 * 64];   // 16 KB
  __shared__ __bf16 sBg[128 * 64];  // 16 KB
  __shared__ __bf16 sBu[128 * 64];  // 16 KB
  const int t = threadIdx.x;
  const int f0 = blockIdx.x * 128;
  const int m0 = blockIdx.y * 128;
  const int lane = t & 63, wv = t >> 6;
  const int wm = wv & 1, wf = wv >> 1;
  const int l15 = lane & 15, quad = lane >> 4;

  int aoff[4], boff[4];
  #pragma unroll
  for (int i = 0; i < 4; ++i) {
    int idx = i * 256 + t, row = idx >> 3, slot = idx & 7;
    aoff[i] = (m0 + row) * 256 + (slot ^ (row & 7)) * 8;
    boff[i] = (f0 + row) * 256 + (slot ^ (row & 7)) * 8;
  }

  floatx4 zero = {0.f, 0.f, 0.f, 0.f};
  floatx4 accg[4][4], accu[4][4];
  #pragma unroll
  for (int i = 0; i < 4; ++i)
    #pragma unroll
    for (int j = 0; j < 4; ++j) { accg[i][j] = zero; accu[i][j] = zero; }

  const int xr = l15 & 7;
  for (int k = 0; k < 4; ++k) {     // k0 = k*64
    const int kk = k * 64;
    #pragma unroll
    for (int i = 0; i < 4; ++i) {
      async16(A  + aoff[i] + kk, &sA[(i * 256 + t) * 8]);
      async16(Bg + boff[i] + kk, &sBg[(i * 256 + t) * 8]);
      async16(Bu + boff[i] + kk, &sBu[(i * 256 + t) * 8]);
    }
    __syncthreads();

    #pragma unroll
    for (int s = 0; s < 2; ++s) {
      const int slot = (s * 4 + quad) ^ xr;
      bf16x8 av[4], bg[4], bu[4];
      #pragma unroll
      for (int i = 0; i < 4; ++i) {
        int r = wm * 64 + i * 16 + l15;
        av[i] = *(const bf16x8*)&sA[r * 64 + slot * 8];
      }
      #pragma unroll
      for (int j = 0; j < 4; ++j) {
        int r = wf * 64 + j * 16 + l15;
        bg[j] = *(const bf16x8*)&sBg[r * 64 + slot * 8];
        bu[j] = *(const bf16x8*)&sBu[r * 64 + slot * 8];
      }
      #pragma unroll
      for (int i = 0; i < 4; ++i)
        #pragma unroll
        for (int j = 0; j < 4; ++j) {
          accg[i][j] = __builtin_amdgcn_mfma_f32_16x16x32_bf16(av[i], bg[j], accg[i][j], 0, 0, 0);
          accu[i][j] = __builtin_amdgcn_mfma_f32_16x16x32_bf16(av[i], bu[j], accu[i][j], 0, 0, 0);
        }
    }
    __syncthreads();
  }

  #pragma unroll
  for (int i = 0; i < 4; ++i)
    #pragma unroll
    for (int j = 0; j < 4; ++j)
      #pragma unroll
      for (int r = 0; r < 4; ++r) {
        int m = m0 + wm * 64 + i * 16 + quad * 4 + r;
        int f = f0 + wf * 64 + j * 16 + l15;
        float gv = accg[i][j][r];
        float uv = accu[i][j][r];
        float hv = (gv / (1.f + __expf(-gv))) * uv;
        H[(size_t)m * 1024 + f] = to_fp8(16.f * hv);   // scaled x16
      }
}

// ---- Kernel D: fp8 down GEMM + residual. tile 128m x 256n, BK=64 ----
// h (x16) and Wd^T (x16) in e4m3; acc = 256*true -> out = x + acc/256.
// LDS rows 64 B; 16B-slot swizzle q^((row>>1)&3) -> <=2-way (free).
__global__ __launch_bounds__(256, 3) void gemm_down(
    const unsigned char* __restrict__ A,   // h fp8 [65536][1024]
    const unsigned char* __restrict__ B,   // Wd^T fp8 [256][1024]
    const float* __restrict__ X,
    float* __restrict__ O)
{
  __shared__ unsigned char sA[128 * 64];   // 8 KB
  __shared__ unsigned char sB[256 * 64];   // 16 KB
  const int t = threadIdx.x;
  const int m0 = blockIdx.x * 128;
  const int lane = t & 63, wv = t >> 6;
  const int wm = wv & 1, wn = wv >> 1;
  const int l15 = lane & 15, quad = lane >> 4;

  int aoff[2], boff[4];
  #pragma unroll
  for (int i = 0; i < 2; ++i) {
    int idx = i * 256 + t, row = idx >> 2, q = idx & 3;
    aoff[i] = (m0 + row) * 1024 + (q ^ ((row >> 1) & 3)) * 16;
  }
  #pragma unroll
  for (int i = 0; i < 4; ++i) {
    int idx = i * 256 + t, row = idx >> 2, q = idx & 3;
    boff[i] = row * 1024 + (q ^ ((row >> 1) & 3)) * 16;
  }

  floatx4 zero = {0.f, 0.f, 0.f, 0.f};
  floatx4 acc[4][8];
  #pragma unroll
  for (int i = 0; i < 4; ++i)
    #pragma unroll
    for (int j = 0; j < 8; ++j) acc[i][j] = zero;

  for (int k = 0; k < 16; ++k) {    // k0 = k*64 (bytes == elements)
    const int kk = k * 64;
    #pragma unroll
    for (int i = 0; i < 2; ++i) async16(A + aoff[i] + kk, &sA[(i * 256 + t) * 16]);
    #pragma unroll
    for (int i = 0; i < 4; ++i) async16(B + boff[i] + kk, &sB[(i * 256 + t) * 16]);
    __syncthreads();

    #pragma unroll
    for (int s = 0; s < 2; ++s) {
      const int u = s * 4 + quad;           // 8-byte subslot 0..7
      long av[4], bv[8];
      #pragma unroll
      for (int i = 0; i < 4; ++i) {
        int r = wm * 64 + i * 16 + l15;
        int byte = r * 64 + (((u >> 1) ^ ((r >> 1) & 3)) << 4) + (u & 1) * 8;
        av[i] = *(const long*)&sA[byte];
      }
      #pragma unroll
      for (int j = 0; j < 8; ++j) {
        int r = wn * 128 + j * 16 + l15;
        int byte = r * 64 + (((u >> 1) ^ ((r >> 1) & 3)) << 4) + (u & 1) * 8;
        bv[j] = *(const long*)&sB[byte];
      }
      #pragma unroll
      for (int i = 0; i < 4; ++i)
        #pragma unroll
        for (int j = 0; j < 8; ++j)
          acc[i][j] = __builtin_amdgcn_mfma_f32_16x16x32_fp8_fp8(av[i], bv[j], acc[i][j], 0, 0, 0);
    }
    __syncthreads();
  }

  #pragma unroll
  for (int i = 0; i < 4; ++i)
    #pragma unroll
    for (int j = 0; j < 8; ++j)
      #pragma unroll
      for (int r = 0; r < 4; ++r) {
        int m = m0 + wm * 64 + i * 16 + quad * 4 + r;
        int n = wn * 128 + j * 16 + l15;
        size_t o = (size_t)m * 256 + n;
        O[o] = X[o] + acc[i][j][r] * (1.f / 256.f);
      }
}

extern "C" void kernel_launch(void* const* d_in, const int* in_sizes, int n_in,
                              void* d_out, int out_size, void* d_ws, size_t ws_size,
                              hipStream_t stream) {
  const float* x   = (const float*)d_in[0];
  const float* iw  = (const float*)d_in[1];
  const float* gg  = (const float*)d_in[2];
  const float* lnw = (const float*)d_in[3];
  const float* lnb = (const float*)d_in[4];
  const float* Wg  = (const float*)d_in[5];
  const float* Wu  = (const float*)d_in[6];
  const float* Wd  = (const float*)d_in[7];
  float* out = (float*)d_out;

  char* ws = (char*)d_ws;
  __bf16*        flat = (__bf16*)(ws);                       // 32 MB
  unsigned char* h    = (unsigned char*)(ws + 33554432);     // 64 MB
  __bf16*        Bg   = (__bf16*)(ws + 100663296);           // 512 KB
  __bf16*        Bu   = (__bf16*)(ws + 101187584);           // 512 KB
  unsigned char* Bd   = (unsigned char*)(ws + 101711872);    // 256 KB

  transpose_cast<<<dim3(32, 8),  256, 0, stream>>>(Wg, Bg, 256, 1024);
  transpose_cast<<<dim3(32, 8),  256, 0, stream>>>(Wu, Bu, 256, 1024);
  transpose_cast_fp8<<<dim3(8, 32), 256, 0, stream>>>(Wd, Bd, 1024, 256);
  geo_ln<<<8192, 256, 0, stream>>>(x, iw, gg, lnw, lnb, flat);
  gemm_gateup<<<dim3(8, 512), 256, 0, stream>>>(flat, Bg, Bu, h);
  gemm_down<<<512, 256, 0, stream>>>(h, Bd, x, out);
}

// Round 5
// 281.194 us; speedup vs baseline: 1.1329x; 1.1329x over previous
//
#include <hip/hip_runtime.h>
#include <hip/hip_bf16.h>
#include <hip/hip_fp8.h>

typedef __bf16 bf16x8 __attribute__((ext_vector_type(8)));
typedef float floatx4 __attribute__((ext_vector_type(4)));
typedef float floatx16 __attribute__((ext_vector_type(16)));

// ---- Cl(3) Cayley table, row i = first operand, col j = second. p = i*8+j ----
constexpr int TK[64] = {
  0,1,2,3,4,5,6,7,
  1,0,4,5,2,3,7,6,
  2,4,0,6,1,7,3,5,
  3,5,6,0,7,1,2,4,
  4,2,1,7,0,6,5,3,
  5,3,7,1,6,0,4,2,
  6,7,3,2,5,4,0,1,
  7,6,5,4,3,2,1,0
};
constexpr float SGN[64] = {
  1, 1, 1, 1, 1, 1, 1, 1,
  1, 1, 1, 1, 1, 1, 1, 1,
  1,-1, 1, 1,-1,-1, 1,-1,
  1,-1,-1, 1, 1,-1,-1, 1,
  1,-1, 1, 1,-1,-1, 1,-1,
  1,-1,-1, 1, 1,-1,-1, 1,
  1, 1,-1, 1,-1, 1,-1,-1,
  1, 1,-1, 1,-1, 1,-1,-1
};

__device__ __forceinline__ void async16(const void* g, void* l) {
  __builtin_amdgcn_global_load_lds(
      (const __attribute__((address_space(1))) void*)g,
      (__attribute__((address_space(3))) void*)l, 16, 0, 0);
}

__device__ __forceinline__ unsigned char to_fp8(float v) {
  __hip_fp8_e4m3 q(v);
  return (unsigned char)q.__x;
}

// ---- transpose+cast fp32 [K][N] -> bf16 [N][K] ----
__global__ __launch_bounds__(256) void transpose_cast(
    const float* __restrict__ src, __bf16* __restrict__ dst, int K, int N)
{
  __shared__ float s[32 * 33];
  const int t = threadIdx.x;
  const int k0 = blockIdx.y * 32, n0 = blockIdx.x * 32;
  const int r = t >> 5, c = t & 31;
  #pragma unroll
  for (int i = 0; i < 4; ++i)
    s[(r + i * 8) * 33 + c] = src[(size_t)(k0 + r + i * 8) * N + n0 + c];
  __syncthreads();
  #pragma unroll
  for (int i = 0; i < 4; ++i)
    dst[(size_t)(n0 + r + i * 8) * K + k0 + c] = (__bf16)s[c * 33 + r + i * 8];
}

// ---- transpose+cast fp32 [K][N] -> fp8 [N][K], value*16 ----
__global__ __launch_bounds__(256) void transpose_cast_fp8(
    const float* __restrict__ src, unsigned char* __restrict__ dst, int K, int N)
{
  __shared__ float s[32 * 33];
  const int t = threadIdx.x;
  const int k0 = blockIdx.y * 32, n0 = blockIdx.x * 32;
  const int r = t >> 5, c = t & 31;
  #pragma unroll
  for (int i = 0; i < 4; ++i)
    s[(r + i * 8) * 33 + c] = src[(size_t)(k0 + r + i * 8) * N + n0 + c];
  __syncthreads();
  #pragma unroll
  for (int i = 0; i < 4; ++i)
    dst[(size_t)(n0 + r + i * 8) * K + k0 + c] = to_fp8(16.f * s[c * 33 + r + i * 8]);
}

// ---- geometric product + gate mix + LayerNorm -> bf16 flat [65536][256] ----
__global__ __launch_bounds__(256) void geo_ln(
    const float* __restrict__ X,   // [8192][8][256]
    const float* __restrict__ IW,  // [64]
    const float* __restrict__ GG,  // [1]
    const float* __restrict__ LW, const float* __restrict__ LB,
    __bf16* __restrict__ F)        // [65536][256]
{
  __shared__ float sw[64];
  __shared__ float smix[8 * 256];
  __shared__ float sstat[16];
  const int t = threadIdx.x;
  const int tok = blockIdx.x;

  if (t < 64) sw[t] = SGN[t] / (1.f + __expf(-IW[t]));

  float xv[8];
  #pragma unroll
  for (int b = 0; b < 8; ++b) xv[b] = X[(size_t)tok * 2048 + b * 256 + t];
  const float g = 1.f / (1.f + __expf(-GG[0]));

  __syncthreads();

  float geo[8] = {0.f, 0.f, 0.f, 0.f, 0.f, 0.f, 0.f, 0.f};
  #pragma unroll
  for (int p = 0; p < 64; ++p)
    geo[TK[p]] += xv[p >> 3] * xv[p & 7] * sw[p];

  float mv[8];
  #pragma unroll
  for (int b = 0; b < 8; ++b) {
    mv[b] = g * geo[b] + (1.f - g) * xv[b];
    smix[b * 256 + t] = mv[b];
  }
  __syncthreads();

  const int wv = t >> 6, lane = t & 63;
  #pragma unroll
  for (int s = 0; s < 2; ++s) {
    int b = wv * 2 + s;
    float v0 = smix[b * 256 + lane];
    float v1 = smix[b * 256 + 64 + lane];
    float v2 = smix[b * 256 + 128 + lane];
    float v3 = smix[b * 256 + 192 + lane];
    float sum = v0 + v1 + v2 + v3;
    float sq  = v0*v0 + v1*v1 + v2*v2 + v3*v3;
    #pragma unroll
    for (int off = 32; off > 0; off >>= 1) {
      sum += __shfl_xor(sum, off, 64);
      sq  += __shfl_xor(sq,  off, 64);
    }
    if (lane == 0) {
      float mu  = sum * (1.f / 256.f);
      float var = sq * (1.f / 256.f) - mu * mu;
      sstat[b]     = mu;
      sstat[8 + b] = rsqrtf(var + 1e-5f);
    }
  }
  __syncthreads();

  const float lw = LW[t], lb = LB[t];
  #pragma unroll
  for (int b = 0; b < 8; ++b) {
    float v = (mv[b] - sstat[b]) * sstat[8 + b] * lw + lb;
    F[(size_t)(tok * 8 + b) * 256 + t] = (__bf16)v;
  }
}

// ---- Kernel C: gate+up GEMM + SwiGLU -> h fp8 (x16) with LDS-packed stores ----
// tile 128m x 64f (r3's verified occupancy shape), BK=64, 32x32x16 MFMA.
// grid (16 f, 512 m) x-fastest. LDS slot swizzle slot^(row&7), conflict-free.
__global__ __launch_bounds__(256, 3) void gemm_gateup(
    const __bf16* __restrict__ A,   // flat [65536][256]
    const __bf16* __restrict__ Bg,  // [1024][256]
    const __bf16* __restrict__ Bu,  // [1024][256]
    unsigned char* __restrict__ H)  // fp8 [65536][1024]
{
  __shared__ __align__(16) char smem[32768];
  __bf16* sA  = (__bf16*)smem;                  // 16 KB [128][64]
  __bf16* sBg = (__bf16*)(smem + 16384);        // 8 KB  [64][64]
  __bf16* sBu = (__bf16*)(smem + 24576);        // 8 KB  [64][64]
  unsigned char* sH = (unsigned char*)(smem + 16384);  // 8 KB alias (post-loop)

  const int t = threadIdx.x;
  const int f0 = blockIdx.x * 64;
  const int m0 = blockIdx.y * 128;
  const int lane = t & 63, wv = t >> 6;
  const int wm = wv & 1, wf = wv >> 1;
  const int l31 = lane & 31, half = lane >> 5;

  int aoff[4], boff[2];
  #pragma unroll
  for (int i = 0; i < 4; ++i) {
    int idx = i * 256 + t, row = idx >> 3, slot = idx & 7;
    aoff[i] = (m0 + row) * 256 + (slot ^ (row & 7)) * 8;
  }
  #pragma unroll
  for (int i = 0; i < 2; ++i) {
    int idx = i * 256 + t, row = idx >> 3, slot = idx & 7;
    boff[i] = (f0 + row) * 256 + (slot ^ (row & 7)) * 8;
  }

  floatx16 accg[2], accu[2];
  #pragma unroll
  for (int i = 0; i < 2; ++i)
    #pragma unroll
    for (int r = 0; r < 16; ++r) { accg[i][r] = 0.f; accu[i][r] = 0.f; }

  const int xr = l31 & 7;
  const int rowA0 = (wm * 64 + l31) * 64;       // element offset of A row
  const int rowA1 = rowA0 + 32 * 64;
  const int rowB  = (wf * 32 + l31) * 64;

  for (int k = 0; k < 4; ++k) {     // k0 = k*64
    const int kk = k * 64;
    #pragma unroll
    for (int i = 0; i < 4; ++i) async16(A + aoff[i] + kk, &sA[(i * 256 + t) * 8]);
    #pragma unroll
    for (int i = 0; i < 2; ++i) {
      async16(Bg + boff[i] + kk, &sBg[(i * 256 + t) * 8]);
      async16(Bu + boff[i] + kk, &sBu[(i * 256 + t) * 8]);
    }
    __syncthreads();

    #pragma unroll
    for (int s = 0; s < 4; ++s) {   // k16 steps
      const int oct = ((s * 2 + half) ^ xr) * 8;
      bf16x8 a0 = *(const bf16x8*)&sA[rowA0 + oct];
      bf16x8 a1 = *(const bf16x8*)&sA[rowA1 + oct];
      bf16x8 bg = *(const bf16x8*)&sBg[rowB + oct];
      bf16x8 bu = *(const bf16x8*)&sBu[rowB + oct];
      accg[0] = __builtin_amdgcn_mfma_f32_32x32x16_bf16(a0, bg, accg[0], 0, 0, 0);
      accu[0] = __builtin_amdgcn_mfma_f32_32x32x16_bf16(a0, bu, accu[0], 0, 0, 0);
      accg[1] = __builtin_amdgcn_mfma_f32_32x32x16_bf16(a1, bg, accg[1], 0, 0, 0);
      accu[1] = __builtin_amdgcn_mfma_f32_32x32x16_bf16(a1, bu, accu[1], 0, 0, 0);
    }
    __syncthreads();
  }

  // epilogue: silu(g)*u -> fp8 bytes into LDS tile [128][64], then coalesced stores
  #pragma unroll
  for (int i = 0; i < 2; ++i)
    #pragma unroll
    for (int r = 0; r < 16; ++r) {
      int crow = (r & 3) + 8 * (r >> 2) + 4 * half;   // C/D row map (m74/m101)
      int m_l = wm * 64 + i * 32 + crow;
      float gv = accg[i][r], uv = accu[i][r];
      float hv = (gv / (1.f + __expf(-gv))) * uv;
      sH[m_l * 64 + wf * 32 + l31] = to_fp8(16.f * hv);
    }
  __syncthreads();
  #pragma unroll
  for (int i = 0; i < 2; ++i) {
    int chunk = i * 256 + t;        // 512 chunks of 16 B
    int m = chunk >> 2, c = chunk & 3;
    *(int4*)&H[(size_t)(m0 + m) * 1024 + f0 + c * 16] = *(const int4*)&sH[m * 64 + c * 16];
  }
}

// ---- Kernel D: fp8 down GEMM + residual. tile 128m x 256n, BK=64 ----
// h (x16) and Wd^T (x16) in e4m3; out = x + acc/256.
__global__ __launch_bounds__(256, 2) void gemm_down(
    const unsigned char* __restrict__ A,   // h fp8 [65536][1024]
    const unsigned char* __restrict__ B,   // Wd^T fp8 [256][1024]
    const float* __restrict__ X,
    float* __restrict__ O)
{
  __shared__ unsigned char sA[128 * 64];   // 8 KB
  __shared__ unsigned char sB[256 * 64];   // 16 KB
  const int t = threadIdx.x;
  const int m0 = blockIdx.x * 128;
  const int lane = t & 63, wv = t >> 6;
  const int wm = wv & 1, wn = wv >> 1;
  const int l15 = lane & 15, quad = lane >> 4;

  int aoff[2], boff[4];
  #pragma unroll
  for (int i = 0; i < 2; ++i) {
    int idx = i * 256 + t, row = idx >> 2, q = idx & 3;
    aoff[i] = (m0 + row) * 1024 + (q ^ ((row >> 1) & 3)) * 16;
  }
  #pragma unroll
  for (int i = 0; i < 4; ++i) {
    int idx = i * 256 + t, row = idx >> 2, q = idx & 3;
    boff[i] = row * 1024 + (q ^ ((row >> 1) & 3)) * 16;
  }

  floatx4 zero = {0.f, 0.f, 0.f, 0.f};
  floatx4 acc[4][8];
  #pragma unroll
  for (int i = 0; i < 4; ++i)
    #pragma unroll
    for (int j = 0; j < 8; ++j) acc[i][j] = zero;

  // precompute LDS frag byte addresses (k-invariant)
  int aaddr[2][4], baddr[2][8];
  #pragma unroll
  for (int s = 0; s < 2; ++s) {
    const int u = s * 4 + quad;
    #pragma unroll
    for (int i = 0; i < 4; ++i) {
      int r = wm * 64 + i * 16 + l15;
      aaddr[s][i] = r * 64 + (((u >> 1) ^ ((r >> 1) & 3)) << 4) + (u & 1) * 8;
    }
    #pragma unroll
    for (int j = 0; j < 8; ++j) {
      int r = wn * 128 + j * 16 + l15;
      baddr[s][j] = r * 64 + (((u >> 1) ^ ((r >> 1) & 3)) << 4) + (u & 1) * 8;
    }
  }

  for (int k = 0; k < 16; ++k) {    // k0 = k*64 (bytes == elements)
    const int kk = k * 64;
    #pragma unroll
    for (int i = 0; i < 2; ++i) async16(A + aoff[i] + kk, &sA[(i * 256 + t) * 16]);
    #pragma unroll
    for (int i = 0; i < 4; ++i) async16(B + boff[i] + kk, &sB[(i * 256 + t) * 16]);
    __syncthreads();

    #pragma unroll
    for (int s = 0; s < 2; ++s) {
      long av[4], bv[8];
      #pragma unroll
      for (int i = 0; i < 4; ++i) av[i] = *(const long*)&sA[aaddr[s][i]];
      #pragma unroll
      for (int j = 0; j < 8; ++j) bv[j] = *(const long*)&sB[baddr[s][j]];
      #pragma unroll
      for (int i = 0; i < 4; ++i)
        #pragma unroll
        for (int j = 0; j < 8; ++j)
          acc[i][j] = __builtin_amdgcn_mfma_f32_16x16x32_fp8_fp8(av[i], bv[j], acc[i][j], 0, 0, 0);
    }
    __syncthreads();
  }

  #pragma unroll
  for (int i = 0; i < 4; ++i)
    #pragma unroll
    for (int j = 0; j < 8; ++j)
      #pragma unroll
      for (int r = 0; r < 4; ++r) {
        int m = m0 + wm * 64 + i * 16 + quad * 4 + r;
        int n = wn * 128 + j * 16 + l15;
        size_t o = (size_t)m * 256 + n;
        O[o] = X[o] + acc[i][j][r] * (1.f / 256.f);
      }
}

extern "C" void kernel_launch(void* const* d_in, const int* in_sizes, int n_in,
                              void* d_out, int out_size, void* d_ws, size_t ws_size,
                              hipStream_t stream) {
  const float* x   = (const float*)d_in[0];
  const float* iw  = (const float*)d_in[1];
  const float* gg  = (const float*)d_in[2];
  const float* lnw = (const float*)d_in[3];
  const float* lnb = (const float*)d_in[4];
  const float* Wg  = (const float*)d_in[5];
  const float* Wu  = (const float*)d_in[6];
  const float* Wd  = (const float*)d_in[7];
  float* out = (float*)d_out;

  char* ws = (char*)d_ws;
  __bf16*        flat = (__bf16*)(ws);                       // 32 MB
  unsigned char* h    = (unsigned char*)(ws + 33554432);     // 64 MB
  __bf16*        Bg   = (__bf16*)(ws + 100663296);           // 512 KB
  __bf16*        Bu   = (__bf16*)(ws + 101187584);           // 512 KB
  unsigned char* Bd   = (unsigned char*)(ws + 101711872);    // 256 KB

  transpose_cast<<<dim3(32, 8),  256, 0, stream>>>(Wg, Bg, 256, 1024);
  transpose_cast<<<dim3(32, 8),  256, 0, stream>>>(Wu, Bu, 256, 1024);
  transpose_cast_fp8<<<dim3(8, 32), 256, 0, stream>>>(Wd, Bd, 1024, 256);
  geo_ln<<<8192, 256, 0, stream>>>(x, iw, gg, lnw, lnb, flat);
  gemm_gateup<<<dim3(16, 512), 256, 0, stream>>>(flat, Bg, Bu, h);
  gemm_down<<<512, 256, 0, stream>>>(h, Bd, x, out);
}